// Round 1
// 1077.447 us; speedup vs baseline: 1.0025x; 1.0025x over previous
//
#include <hip/hip_runtime.h>

typedef unsigned short u16;
typedef __bf16 bf16x8 __attribute__((ext_vector_type(8)));
typedef float floatx4 __attribute__((ext_vector_type(4)));

#define NN 50000
#define NE 800000
#define HID 128
#define K1PAD 288     // 273 padded to 288 (9 k-steps of 32)
#define APITCH 296    // e_in LDS pitch (u16): 148 words/row -> minimal-alias banks
#define MPITCH 136    // node m1 LDS pitch
#define A2PITCH 264   // node n_in pitch (K=256 + 8)

__device__ __forceinline__ u16 f2bf(float x) {
  unsigned u = __float_as_uint(x);
  u += 0x7FFFu + ((u >> 16) & 1u);   // RNE; inputs are finite
  return (u16)(u >> 16);
}
__device__ __forceinline__ float silu_f(float x) {
  return x / (1.0f + __expf(-x));
}

// One chained-GEMM stage: C[64x128] += A_lds[64xK] * Wt[K x 128 (stored n-major)]
// B fragments are loaded straight from global (weights are tiny & L2-resident):
// no LDS staging, NO barriers inside the k-loop.
// 4 waves: wave=(wm,wn); wave computes rows wm*32..+32, cols wn*64..+64 (2x4 tiles).
__device__ __forceinline__ void do_gemm_regB(
    const u16* __restrict__ Alds, const int apitch,
    const u16* __restrict__ Wt, const int wpitch, const int ksteps,
    floatx4 acc[2][4],
    const int wm, const int wn, const int ln, const int quad)
{
  const u16* wb = Wt + (size_t)(wn*64 + ln) * wpitch + quad*8;
  const u16* ab = Alds + (wm*32 + ln) * apitch + quad*8;
#pragma unroll
  for (int ks = 0; ks < ksteps; ++ks) {
    const int k0 = ks * 32;
    bf16x8 a[2], b[4];
#pragma unroll
    for (int tm = 0; tm < 2; ++tm)
      a[tm] = *(const bf16x8*)(ab + tm*16*apitch + k0);
#pragma unroll
    for (int tn = 0; tn < 4; ++tn)
      b[tn] = *(const bf16x8*)(wb + tn*16*wpitch + k0);
#pragma unroll
    for (int tm = 0; tm < 2; ++tm)
#pragma unroll
      for (int tn = 0; tn < 4; ++tn)
        acc[tm][tn] = __builtin_amdgcn_mfma_f32_16x16x32_bf16(a[tm], b[tn], acc[tm][tn], 0, 0, 0);
  }
}

__global__ void pack_weights(const float* __restrict__ We1, const float* __restrict__ We2,
                             const float* __restrict__ Wn1, const float* __restrict__ Wn2,
                             const float* __restrict__ Wc1,
                             u16* We1t, u16* We2t, u16* Wn1t, u16* Wn2t, u16* Wc1t)
{
  const int n = blockIdx.x;      // output feature 0..127
  const int t = threadIdx.x;     // 0..255
  for (int k = t; k < K1PAD; k += 256)
    We1t[n * K1PAD + k] = (k < 273) ? f2bf(We1[k * HID + n]) : (u16)0;
  for (int k = t; k < 256; k += 256)
    Wn1t[n * 256 + k] = f2bf(Wn1[k * HID + n]);
  if (t < HID) {
    We2t[n * HID + t] = f2bf(We2[t * HID + n]);
    Wn2t[n * HID + t] = f2bf(Wn2[t * HID + n]);
    Wc1t[n * HID + t] = f2bf(Wc1[t * HID + n]);
  }
}

__global__ void conv_h(const float* __restrict__ h, u16* __restrict__ hb) {
  const int i = (blockIdx.x * 256 + threadIdx.x) * 4;   // 6250*256*4 == 6.4M exact
  float4 v = *(const float4*)(h + i);
  ushort4 o;
  o.x = f2bf(v.x); o.y = f2bf(v.y); o.z = f2bf(v.z); o.w = f2bf(v.w);
  *(ushort4*)(hb + i) = o;
}

__global__ void __launch_bounds__(256, 4) edge_kernel(
    const u16* __restrict__ hb, const float* __restrict__ coord,
    const float* __restrict__ eattr, const int* __restrict__ eidx,
    const u16* __restrict__ We1t, const float* __restrict__ be1,
    const u16* __restrict__ We2t, const float* __restrict__ be2,
    const u16* __restrict__ Wc1t, const float* __restrict__ bc1,
    const float* __restrict__ Wc2, const float* __restrict__ bc2,
    float* __restrict__ m_out, float* __restrict__ agg,
    float* __restrict__ sacc, float* __restrict__ cnt)
{
  __shared__ __align__(16) u16 A[64 * APITCH];      // e_in; cols reused: m1 -> [0,128), mB -> [128,256)
  __shared__ int rows_s[64];
  __shared__ float dc_s[64 * 3];
  __shared__ float wbuf[64 * 2];

  const int tid = threadIdx.x;
  const int e0 = blockIdx.x * 64;

  // ---- build e_in tile: [h[row] | h[col] | radial | edge_attr | 0-pad] ----
  {
    const int e = tid >> 2, p = tid & 3;   // 4 threads per edge
    const int ge = e0 + e;
    const int r = eidx[ge];
    const int c = eidx[NE + ge];
    u16* dstA = A + e * APITCH;
    const u16* hr = hb + (size_t)r * HID;
    const u16* hc = hb + (size_t)c * HID;
#pragma unroll
    for (int j = 0; j < 4; ++j) {
      const int col = p * 32 + j * 8;
      *(int4*)(dstA + col)       = *(const int4*)(hr + col);
      *(int4*)(dstA + HID + col) = *(const int4*)(hc + col);
    }
    float4 ea = *(const float4*)(eattr + (size_t)ge * 16 + p * 4);
    dstA[257 + p*4 + 0] = f2bf(ea.x);
    dstA[257 + p*4 + 1] = f2bf(ea.y);
    dstA[257 + p*4 + 2] = f2bf(ea.z);
    dstA[257 + p*4 + 3] = f2bf(ea.w);
    if (p == 3) {
      rows_s[e] = r;
      float dx = coord[r*3+0] - coord[c*3+0];
      float dy = coord[r*3+1] - coord[c*3+1];
      float dz = coord[r*3+2] - coord[c*3+2];
      dc_s[e*3+0] = dx; dc_s[e*3+1] = dy; dc_s[e*3+2] = dz;
      dstA[256] = f2bf(dx*dx + dy*dy + dz*dz);
    } else {
      for (int i = 0; i < 5; ++i) dstA[273 + p*5 + i] = 0;  // zero cols 273..287
    }
  }

  const int wave = tid >> 6;
  const int wm = wave >> 1, wn = wave & 1;
  const int ln = tid & 15, quad = (tid >> 4) & 3;
  const floatx4 z4 = {0.f, 0.f, 0.f, 0.f};
  floatx4 acc[2][4];

  __syncthreads();                                   // (1) A built

  // ===== GEMM1: e_in(64x288) @ We1 -> silu -> m1 (into A cols [0,128)) =====
#pragma unroll
  for (int tm = 0; tm < 2; ++tm)
#pragma unroll
    for (int tn = 0; tn < 4; ++tn) acc[tm][tn] = z4;
  do_gemm_regB(A, APITCH, We1t, K1PAD, 9, acc, wm, wn, ln, quad);
  __syncthreads();                                   // (2) all G1 A-reads done
#pragma unroll
  for (int tm = 0; tm < 2; ++tm)
#pragma unroll
    for (int tn = 0; tn < 4; ++tn) {
      const int colg = wn*64 + tn*16 + ln;
      const float bias = be1[colg];
#pragma unroll
      for (int i = 0; i < 4; ++i) {
        const int rowl = wm*32 + tm*16 + quad*4 + i;
        A[rowl * APITCH + colg] = f2bf(silu_f(acc[tm][tn][i] + bias));
      }
    }
  __syncthreads();                                   // (3) m1 visible

  // ===== GEMM2: m1 @ We2 -> silu -> m  (m fp32 out + agg atomics + bf16 into A cols [128,256)) =====
#pragma unroll
  for (int tm = 0; tm < 2; ++tm)
#pragma unroll
    for (int tn = 0; tn < 4; ++tn) acc[tm][tn] = z4;
  do_gemm_regB(A, APITCH, We2t, HID, 4, acc, wm, wn, ln, quad);
  // epilogue writes cols [128,256): disjoint from G2's reads of cols [0,128) -> no barrier needed
#pragma unroll
  for (int tm = 0; tm < 2; ++tm)
#pragma unroll
    for (int tn = 0; tn < 4; ++tn) {
      const int colg = wn*64 + tn*16 + ln;
      const float bias = be2[colg];
#pragma unroll
      for (int i = 0; i < 4; ++i) {
        const int rowl = wm*32 + tm*16 + quad*4 + i;
        const float v = silu_f(acc[tm][tn][i] + bias);
        __builtin_nontemporal_store(v, &m_out[(size_t)(e0 + rowl) * HID + colg]);
        atomicAdd(&agg[(size_t)rows_s[rowl] * HID + colg], v);
        A[rowl * APITCH + HID + colg] = f2bf(v);
      }
    }
  __syncthreads();                                   // (4) m(bf16) visible

  // ===== GEMM3: m @ Wc1 -> silu -> dot with Wc2 -> per-edge scalar w =====
#pragma unroll
  for (int tm = 0; tm < 2; ++tm)
#pragma unroll
    for (int tn = 0; tn < 4; ++tn) acc[tm][tn] = z4;
  do_gemm_regB(A + HID, APITCH, Wc1t, HID, 4, acc, wm, wn, ln, quad);
  float wr[2][4] = {{0.f,0.f,0.f,0.f},{0.f,0.f,0.f,0.f}};
#pragma unroll
  for (int tm = 0; tm < 2; ++tm)
#pragma unroll
    for (int tn = 0; tn < 4; ++tn) {
      const int colg = wn*64 + tn*16 + ln;
      const float bias = bc1[colg];
      const float wc2 = Wc2[colg];
#pragma unroll
      for (int i = 0; i < 4; ++i)
        wr[tm][i] += silu_f(acc[tm][tn][i] + bias) * wc2;
    }
#pragma unroll
  for (int tm = 0; tm < 2; ++tm)
#pragma unroll
    for (int i = 0; i < 4; ++i) {
      float v = wr[tm][i];
      v += __shfl_xor(v, 1);
      v += __shfl_xor(v, 2);
      v += __shfl_xor(v, 4);
      v += __shfl_xor(v, 8);
      if (ln == 0) wbuf[(wm*32 + tm*16 + quad*4 + i) * 2 + wn] = v;
    }
  __syncthreads();                                   // (5) wbuf ready
  if (tid < 64) {
    const float w = wbuf[tid*2] + wbuf[tid*2 + 1] + bc2[0];
    const int rr = rows_s[tid];
    atomicAdd(&sacc[rr*3 + 0], dc_s[tid*3 + 0] * w);
    atomicAdd(&sacc[rr*3 + 1], dc_s[tid*3 + 1] * w);
    atomicAdd(&sacc[rr*3 + 2], dc_s[tid*3 + 2] * w);
    atomicAdd(&cnt[rr], 1.0f);
  }
}

__global__ void __launch_bounds__(256, 3) node_kernel(
    const u16* __restrict__ hb, const float* __restrict__ agg,
    const u16* __restrict__ Wn1t, const float* __restrict__ bn1,
    const u16* __restrict__ Wn2t, const float* __restrict__ bn2,
    const float* __restrict__ coord, const float* __restrict__ sacc,
    const float* __restrict__ cnt,
    float* __restrict__ hout, float* __restrict__ coordout)
{
  __shared__ __align__(16) u16 A2[64 * A2PITCH];
  __shared__ __align__(16) u16 M1[64 * MPITCH];
  const int tid = threadIdx.x;
  const int n0 = blockIdx.x * 64;

  { // build n_in = [h | agg] in bf16
    const int e = tid >> 2, p = tid & 3;
    const int node = n0 + e;
    u16* dstA = A2 + e * A2PITCH;
    if (node < NN) {
      const u16* hr = hb + (size_t)node * HID;
#pragma unroll
      for (int j = 0; j < 4; ++j) {
        const int col = p * 32 + j * 8;
        *(int4*)(dstA + col) = *(const int4*)(hr + col);
      }
      const float* ar = agg + (size_t)node * HID;
#pragma unroll
      for (int j = 0; j < 8; ++j) {
        const int col = p * 32 + j * 4;
        float4 v = *(const float4*)(ar + col);
        ushort4 o;
        o.x = f2bf(v.x); o.y = f2bf(v.y); o.z = f2bf(v.z); o.w = f2bf(v.w);
        *(ushort4*)(dstA + HID + col) = o;
      }
    } else {
      const int4 zz = {0, 0, 0, 0};
#pragma unroll
      for (int j = 0; j < 4; ++j) {
        const int col = p * 32 + j * 8;
        *(int4*)(dstA + col) = zz;
        *(int4*)(dstA + HID + col) = zz;
      }
    }
  }

  const int wave = tid >> 6;
  const int wm = wave >> 1, wn = wave & 1;
  const int ln = tid & 15, quad = (tid >> 4) & 3;
  const floatx4 z4 = {0.f, 0.f, 0.f, 0.f};
  floatx4 acc[2][4];

  __syncthreads();                                   // (1) A2 built

  // GEMM1: n_in(64x256) @ Wn1 -> silu -> M1
#pragma unroll
  for (int tm = 0; tm < 2; ++tm)
#pragma unroll
    for (int tn = 0; tn < 4; ++tn) acc[tm][tn] = z4;
  do_gemm_regB(A2, A2PITCH, Wn1t, 256, 8, acc, wm, wn, ln, quad);
  // epilogue writes M1 (separate buffer) -> safe while others still read A2
#pragma unroll
  for (int tm = 0; tm < 2; ++tm)
#pragma unroll
    for (int tn = 0; tn < 4; ++tn) {
      const int colg = wn*64 + tn*16 + ln;
      const float bias = bn1[colg];
#pragma unroll
      for (int i = 0; i < 4; ++i) {
        const int rowl = wm*32 + tm*16 + quad*4 + i;
        M1[rowl * MPITCH + colg] = f2bf(silu_f(acc[tm][tn][i] + bias));
      }
    }
  __syncthreads();                                   // (2) M1 visible

  // GEMM2: M1 @ Wn2 + bn2 -> h_out (no activation)
#pragma unroll
  for (int tm = 0; tm < 2; ++tm)
#pragma unroll
    for (int tn = 0; tn < 4; ++tn) acc[tm][tn] = z4;
  do_gemm_regB(M1, MPITCH, Wn2t, HID, 4, acc, wm, wn, ln, quad);
#pragma unroll
  for (int tm = 0; tm < 2; ++tm)
#pragma unroll
    for (int tn = 0; tn < 4; ++tn) {
      const int colg = wn*64 + tn*16 + ln;
      const float bias = bn2[colg];
#pragma unroll
      for (int i = 0; i < 4; ++i) {
        const int rowl = wm*32 + tm*16 + quad*4 + i;
        const int node = n0 + rowl;
        if (node < NN) hout[(size_t)node * HID + colg] = acc[tm][tn][i] + bias;
      }
    }

  // coord epilogue (global-only reads; no LDS dependency)
  if (tid < 64) {
    const int node = n0 + tid;
    if (node < NN) {
      const float cv = fmaxf(cnt[node], 1.0f);
#pragma unroll
      for (int c = 0; c < 3; ++c)
        coordout[node*3 + c] = coord[node*3 + c] + sacc[node*3 + c] / cv;
    }
  }
}

extern "C" void kernel_launch(void* const* d_in, const int* in_sizes, int n_in,
                              void* d_out, int out_size, void* d_ws, size_t ws_size,
                              hipStream_t stream)
{
  const float* h     = (const float*)d_in[0];
  const float* coord = (const float*)d_in[1];
  const float* eattr = (const float*)d_in[2];
  const int*   eidx  = (const int*)d_in[3];
  const float* We1 = (const float*)d_in[4];  const float* be1 = (const float*)d_in[5];
  const float* We2 = (const float*)d_in[6];  const float* be2 = (const float*)d_in[7];
  const float* Wn1 = (const float*)d_in[8];  const float* bn1 = (const float*)d_in[9];
  const float* Wn2 = (const float*)d_in[10]; const float* bn2 = (const float*)d_in[11];
  const float* Wc1 = (const float*)d_in[12]; const float* bc1 = (const float*)d_in[13];
  const float* Wc2 = (const float*)d_in[14]; const float* bc2 = (const float*)d_in[15];

  char* ws = (char*)d_ws;
  float* agg  = (float*)(ws);                 // 50000*128*4 = 25,600,000 B (zeroed)
  float* sacc = (float*)(ws + 25600000);      //   600,000 B (zeroed)
  float* cnt  = (float*)(ws + 26200000);      //   200,000 B (zeroed)
  u16* We1t = (u16*)(ws + 26400000);          //    73,728 B
  u16* We2t = (u16*)(ws + 26473728);          //    32,768 B
  u16* Wn1t = (u16*)(ws + 26506496);          //    65,536 B
  u16* Wn2t = (u16*)(ws + 26572032);          //    32,768 B
  u16* Wc1t = (u16*)(ws + 26604800);          //    32,768 B
  u16* hb   = (u16*)(ws + 26637568);          // 12,800,000 B  (total ~39.4 MB)

  float* hout     = (float*)d_out;                      // [50000,128]
  float* coordout = hout + (size_t)NN * HID;            // [50000,3]
  float* m_out    = coordout + (size_t)NN * 3;          // [800000,128]

  hipMemsetAsync(d_ws, 0, 26400000, stream);            // agg + sacc + cnt
  pack_weights<<<128, 256, 0, stream>>>(We1, We2, Wn1, Wn2, Wc1, We1t, We2t, Wn1t, Wn2t, Wc1t);
  conv_h<<<6250, 256, 0, stream>>>(h, hb);
  edge_kernel<<<NE / 64, 256, 0, stream>>>(hb, coord, eattr, eidx,
                                           We1t, be1, We2t, be2, Wc1t, bc1, Wc2, bc2,
                                           m_out, agg, sacc, cnt);
  node_kernel<<<(NN + 63) / 64, 256, 0, stream>>>(hb, agg, Wn1t, bn1, Wn2t, bn2,
                                                  coord, sacc, cnt, hout, coordout);
}